// Round 4
// baseline (138.151 us; speedup 1.0000x reference)
//
#include <hip/hip_runtime.h>

// B=4, T=4096, E=1024, H=64.
// out = Q @ M_b,  M_b = (1/32) * K_b^T V_b,  Q/K/V = idx@W + b   (linear attention:
// reference applies no mask/softmax). Scale folded into Wk/bk.

typedef __attribute__((ext_vector_type(8))) short bf16x8;   // 8 bf16 = 4 VGPRs
typedef __attribute__((ext_vector_type(4))) float f32x4;    // MFMA C/D

#define MFMA16(a, b, c) __builtin_amdgcn_mfma_f32_16x16x32_bf16((a), (b), (c), 0, 0, 0)

__device__ __forceinline__ unsigned short f2bf(float f) {
    unsigned int u = __float_as_uint(f);
    u += 0x7fffu + ((u >> 16) & 1u);          // round-to-nearest-even
    return (unsigned short)(u >> 16);
}

// ---------------------------------------------------------------------------
// K0: weights -> MFMA-fragment order.
// Chunk index t = (k0i*12 + nt)*64 + lane holds 8 bf16:
//   W^T[n][k], n = nt*16 + (lane&15), k = k0i*32 + (lane>>4)*8 + j.
// n<64 -> Wq, n<128 -> Wk * 1/32, else Wv.   (W is [k][h] in memory)
__global__ void prep(const float* __restrict__ Wq, const float* __restrict__ Wk,
                     const float* __restrict__ Wv, unsigned short* __restrict__ WB) {
    int t = blockIdx.x * 256 + threadIdx.x;   // 96 blocks -> 24576 chunks
    int k0i = t / 768;
    int rem = t - k0i * 768;
    int nt = rem >> 6, lane = rem & 63;
    int n = nt * 16 + (lane & 15);
    int kb = k0i * 32 + ((lane >> 4) * 8);
    int mm = n >> 6, h = n & 63;
    const float* W = (mm == 0) ? Wq : (mm == 1) ? Wk : Wv;
    float sc = (mm == 1) ? 0.03125f : 1.0f;
    bf16x8 v;
    #pragma unroll
    for (int j = 0; j < 8; j++) v[j] = (short)f2bf(W[(size_t)(kb + j) * 64 + h] * sc);
    *(bf16x8*)(WB + (size_t)t * 8) = v;
}

// ---------------------------------------------------------------------------
// K1: fused QKV projection — A-first streaming.
// Block = 16 rows x 4 K-split waves (K=256 each); grid 1024.
// Each wave issues ALL 16 A float4 loads up-front (16KB/wave in flight ->
// Little's law saturates HBM at >=12 waves/CU), converts to bf16 as they land,
// then K-loop: 12 B fragments/iter straight from L2-hot WB + 12 MFMAs.
// End: 2-stage LDS tree reduction across the 4 K-split waves; kh0 epilogue.
__global__ __launch_bounds__(256, 3) void qkv(
    const float* __restrict__ idx, const unsigned short* __restrict__ WB,
    const float* __restrict__ bq, const float* __restrict__ bk, const float* __restrict__ bv,
    unsigned short* __restrict__ Q, unsigned short* __restrict__ Kt,
    unsigned short* __restrict__ Vt) {
    __shared__ float red[2][64][49];                // 24.5 KB, 2-way LDS access (free)
    const int lane = threadIdx.x & 63, kh = threadIdx.x >> 6;
    const int r0 = blockIdx.x * 16;

    const float* aP = idx + (size_t)(r0 + (lane & 15)) * 1024 + kh * 256 + ((lane >> 4) * 8);

    // ---- issue ALL A loads up-front (maximum memory-level parallelism) ----
    float4 af[16];
    #pragma unroll
    for (int it = 0; it < 8; it++) {
        af[it * 2]     = *(const float4*)(aP + it * 32);
        af[it * 2 + 1] = *(const float4*)(aP + it * 32 + 4);
    }
    bf16x8 aF[8];
    #pragma unroll
    for (int it = 0; it < 8; it++) {
        float4 lo = af[it * 2], hi = af[it * 2 + 1];
        bf16x8 a;
        a[0] = (short)f2bf(lo.x); a[1] = (short)f2bf(lo.y);
        a[2] = (short)f2bf(lo.z); a[3] = (short)f2bf(lo.w);
        a[4] = (short)f2bf(hi.x); a[5] = (short)f2bf(hi.y);
        a[6] = (short)f2bf(hi.z); a[7] = (short)f2bf(hi.w);
        aF[it] = a;
    }

    const f32x4 z4 = {0.f, 0.f, 0.f, 0.f};
    f32x4 acc[12];
    #pragma unroll
    for (int i = 0; i < 12; i++) acc[i] = z4;

    #pragma unroll
    for (int i = 0; i < 8; i++) {
        const unsigned short* Bp = WB + (size_t)(((kh * 8 + i) * 12) * 64 + lane) * 8;
        #pragma unroll
        for (int nt = 0; nt < 12; nt++) {
            bf16x8 bb = *(const bf16x8*)(Bp + nt * 512);   // 1KB coalesced, L2-hot
            acc[nt] = MFMA16(aF[i], bb, acc[nt]);
        }
    }

    // --- K-split tree reduction: final = (kh0+kh2) + (kh1+kh3) ---
    if (kh >= 2) {
        #pragma unroll
        for (int nt = 0; nt < 12; nt++)
            #pragma unroll
            for (int reg = 0; reg < 4; reg++)
                red[kh - 2][lane][nt * 4 + reg] = acc[nt][reg];
    }
    __syncthreads();
    if (kh < 2) {
        #pragma unroll
        for (int nt = 0; nt < 12; nt++)
            #pragma unroll
            for (int reg = 0; reg < 4; reg++)
                acc[nt][reg] += red[kh][lane][nt * 4 + reg];
    }
    __syncthreads();
    if (kh == 1) {
        #pragma unroll
        for (int nt = 0; nt < 12; nt++)
            #pragma unroll
            for (int reg = 0; reg < 4; reg++)
                red[0][lane][nt * 4 + reg] = acc[nt][reg];
    }
    __syncthreads();
    if (kh == 0) {
        // epilogue: C/D layout col=lane&15, row=(lane>>4)*4+reg
        #pragma unroll
        for (int nt = 0; nt < 12; nt++) {
            int m = nt >> 2;                       // 0=Q 1=K 2=V
            int h = (nt & 3) * 16 + (lane & 15);
            float bias = (m == 0) ? bq[h] : (m == 1) ? bk[h] * 0.03125f : bv[h];
            int rbase = r0 + (lane >> 4) * 4;
            #pragma unroll
            for (int reg = 0; reg < 4; reg++) {
                float s = acc[nt][reg] + red[0][lane][nt * 4 + reg] + bias;
                int r = rbase + reg;
                unsigned short v = f2bf(s);
                if (m == 0) {
                    Q[(size_t)r * 64 + h] = v;
                } else {
                    int b = r >> 12, t = r & 4095;
                    unsigned short* dst = (m == 1) ? Kt : Vt;
                    dst[(size_t)b * 262144 + h * 4096 + t] = v;
                }
            }
        }
    }
}

// ---------------------------------------------------------------------------
// K2: partial M over 32 T-chunks of 128: part[b][c] = Kt_chunk @ Vt_chunk^T (fp32)
__global__ __launch_bounds__(256) void ktv_partial(
    const unsigned short* __restrict__ Kt, const unsigned short* __restrict__ Vt,
    float* __restrict__ part) {
    const int lane = threadIdx.x & 63, wave = threadIdx.x >> 6;
    const int c = blockIdx.x, b = blockIdx.y;
    const unsigned short* Kb = Kt + (size_t)b * 262144;
    const unsigned short* Vb = Vt + (size_t)b * 262144;
    const f32x4 z4 = {0.f, 0.f, 0.f, 0.f};
    f32x4 acc[4] = {z4, z4, z4, z4};
    const int m  = 16 * wave + (lane & 15);
    const int tq = (lane >> 4) * 8;
    #pragma unroll
    for (int it = 0; it < 4; it++) {
        int t0 = c * 128 + it * 32 + tq;
        bf16x8 a = *(const bf16x8*)&Kb[(size_t)m * 4096 + t0];
        #pragma unroll
        for (int nt = 0; nt < 4; nt++) {
            bf16x8 bb = *(const bf16x8*)&Vb[(size_t)(nt * 16 + (lane & 15)) * 4096 + t0];
            acc[nt] = MFMA16(a, bb, acc[nt]);
        }
    }
    float* P = part + (size_t)(b * 32 + c) * 4096;
    const int rowb = 16 * wave + (lane >> 4) * 4;
    #pragma unroll
    for (int nt = 0; nt < 4; nt++)
        #pragma unroll
        for (int reg = 0; reg < 4; reg++)
            P[(rowb + reg) * 64 + nt * 16 + (lane & 15)] = acc[nt][reg];
}

// ---------------------------------------------------------------------------
// K3: M reduce over 32 chunks; store TRANSPOSED bf16: Mt[b][h2][h1]
__global__ void reduce_m(const float* __restrict__ part,
                         unsigned short* __restrict__ Mt) {
    int i = blockIdx.x * 256 + threadIdx.x;         // 16384 -> grid 64
    int b = i >> 12, h1 = (i >> 6) & 63, h2 = i & 63;
    float s = 0.f;
    #pragma unroll
    for (int cc = 0; cc < 32; cc++)
        s += part[(size_t)(b * 32 + cc) * 4096 + h1 * 64 + h2];
    Mt[(size_t)b * 4096 + h2 * 64 + h1] = f2bf(s);
}

// ---------------------------------------------------------------------------
// K4: out[r][h2] = Q[r][:] @ M_b[:, h2], fp32 out.
__global__ __launch_bounds__(256) void qm(
    const unsigned short* __restrict__ Q, const unsigned short* __restrict__ Mt,
    float* __restrict__ out) {
    const int lane = threadIdx.x & 63, wave = threadIdx.x >> 6;
    const int r0 = blockIdx.x * 64;
    const int b  = r0 >> 12;
    const f32x4 z4 = {0.f, 0.f, 0.f, 0.f};
    f32x4 acc[4] = {z4, z4, z4, z4};
    const int rr = r0 + 16 * wave + (lane & 15);
    const int kq = (lane >> 4) * 8;
    #pragma unroll
    for (int ks = 0; ks < 2; ks++) {
        int k0 = ks * 32;
        bf16x8 a = *(const bf16x8*)&Q[(size_t)rr * 64 + k0 + kq];
        #pragma unroll
        for (int nt = 0; nt < 4; nt++) {
            bf16x8 bb = *(const bf16x8*)&Mt[(size_t)b * 4096 + (nt * 16 + (lane & 15)) * 64 + k0 + kq];
            acc[nt] = MFMA16(a, bb, acc[nt]);
        }
    }
    const int rowb = r0 + 16 * wave + (lane >> 4) * 4;
    #pragma unroll
    for (int nt = 0; nt < 4; nt++)
        #pragma unroll
        for (int reg = 0; reg < 4; reg++)
            out[(size_t)(rowb + reg) * 64 + nt * 16 + (lane & 15)] = acc[nt][reg];
}

// ---------------------------------------------------------------------------
// Workspace layout (ws is ~268 MB per the harness fill — plenty):
//   [0, 384K)    WB   (dead after qkv)
//   [0, 2M)      Pp   (written by ktv_partial AFTER qkv -> safe reuse of WB)
//   [2M, 4M)     Q
//   [4M, 6M)     Kt
//   [6M, 8M)     Vt
//   [8M, 8M+32K) Mt
extern "C" void kernel_launch(void* const* d_in, const int* in_sizes, int n_in,
                              void* d_out, int out_size, void* d_ws, size_t ws_size,
                              hipStream_t stream) {
    const float* idx = (const float*)d_in[0];
    const float* Wq  = (const float*)d_in[1];
    const float* bq  = (const float*)d_in[2];
    const float* Wk  = (const float*)d_in[3];
    const float* bk  = (const float*)d_in[4];
    const float* Wv  = (const float*)d_in[5];
    const float* bv  = (const float*)d_in[6];
    float* out = (float*)d_out;

    char* ws = (char*)d_ws;
    unsigned short* WB = (unsigned short*)(ws);
    float*          Pp = (float*)(ws);
    unsigned short* Q  = (unsigned short*)(ws + (2048u << 10));
    unsigned short* Kt = (unsigned short*)(ws + (4096u << 10));
    unsigned short* Vt = (unsigned short*)(ws + (6144u << 10));
    unsigned short* Mt = (unsigned short*)(ws + (8192u << 10));

    hipLaunchKernelGGL(prep,        dim3(96),     dim3(256), 0, stream, Wq, Wk, Wv, WB);
    hipLaunchKernelGGL(qkv,         dim3(1024),   dim3(256), 0, stream,
                       idx, WB, bq, bk, bv, Q, Kt, Vt);
    hipLaunchKernelGGL(ktv_partial, dim3(32, 4),  dim3(256), 0, stream, Kt, Vt, Pp);
    hipLaunchKernelGGL(reduce_m,    dim3(64),     dim3(256), 0, stream, Pp, Mt);
    hipLaunchKernelGGL(qm,          dim3(256),    dim3(256), 0, stream, Q, Mt, out);
}

// Round 5
// 129.683 us; speedup vs baseline: 1.0653x; 1.0653x over previous
//
#include <hip/hip_runtime.h>

// B=4, T=4096, E=1024, H=64.
// out = Q @ M_b,  M_b = (1/32) * K_b^T V_b,  Q/K/V = idx@W + b   (linear attention:
// reference applies no mask/softmax). Scale folded into Wk/bk.
//
// R5 key change: qkv reads idx SEQUENTIALLY (1KB contiguous per wave-instruction
// via global_load_lds) and does the MFMA-fragment scatter from LDS. R1-R4 all
// read idx as 16B/lane over 16 rows at 4KB stride -> ~900 GB/s scatter ceiling.

typedef __attribute__((ext_vector_type(8))) short bf16x8;   // 8 bf16 = 4 VGPRs
typedef __attribute__((ext_vector_type(4))) float f32x4;    // MFMA C/D

#define MFMA16(a, b, c) __builtin_amdgcn_mfma_f32_16x16x32_bf16((a), (b), (c), 0, 0, 0)

__device__ __forceinline__ unsigned short f2bf(float f) {
    unsigned int u = __float_as_uint(f);
    u += 0x7fffu + ((u >> 16) & 1u);          // round-to-nearest-even
    return (unsigned short)(u >> 16);
}

__device__ __forceinline__ void load_lds16(const float* g, float* l) {
    // async global->LDS, 16B per lane; LDS dest = wave-uniform base + lane*16
    __builtin_amdgcn_global_load_lds(
        (const __attribute__((address_space(1))) unsigned int*)g,
        (__attribute__((address_space(3))) unsigned int*)l, 16, 0, 0);
}

// ---------------------------------------------------------------------------
// K0: weights -> MFMA-fragment order.
// Chunk index t = (k0i*12 + nt)*64 + lane holds 8 bf16:
//   W^T[n][k], n = nt*16 + (lane&15), k = k0i*32 + (lane>>4)*8 + j.
// n<64 -> Wq, n<128 -> Wk * 1/32, else Wv.   (W is [k][h] in memory)
__global__ void prep(const float* __restrict__ Wq, const float* __restrict__ Wk,
                     const float* __restrict__ Wv, unsigned short* __restrict__ WB) {
    int t = blockIdx.x * 256 + threadIdx.x;   // 96 blocks -> 24576 chunks
    int k0i = t / 768;
    int rem = t - k0i * 768;
    int nt = rem >> 6, lane = rem & 63;
    int n = nt * 16 + (lane & 15);
    int kb = k0i * 32 + ((lane >> 4) * 8);
    int mm = n >> 6, h = n & 63;
    const float* W = (mm == 0) ? Wq : (mm == 1) ? Wk : Wv;
    float sc = (mm == 1) ? 0.03125f : 1.0f;
    bf16x8 v;
    #pragma unroll
    for (int j = 0; j < 8; j++) v[j] = (short)f2bf(W[(size_t)(kb + j) * 64 + h] * sc);
    *(bf16x8*)(WB + (size_t)t * 8) = v;
}

// ---------------------------------------------------------------------------
// K1: fused QKV projection — sequential idx streaming through LDS.
// Block = 32 rows, 4 waves; grid 512 (2 blocks/CU). 4 stages of BK=256 floats.
// Stage load: each wave-instruction = ONE contiguous 1KB row-chunk of idx
// (global_load_lds w16). Fragments built by LDS reads (scatter in LDS is cheap).
// Each wave owns n-tiles {w, w+4, w+8} (one Q, one K, one V) over all 32 rows,
// full K accumulated in regs -> no cross-wave reduction.
__global__ __launch_bounds__(256, 2) void qkv(
    const float* __restrict__ idx, const unsigned short* __restrict__ WB,
    const float* __restrict__ bq, const float* __restrict__ bk, const float* __restrict__ bv,
    unsigned short* __restrict__ Q, unsigned short* __restrict__ Kt,
    unsigned short* __restrict__ Vt) {
    __shared__ float As[2][32][260];               // 65 KB total, +4 pad (16B-aligned rows)
    const int lane = threadIdx.x & 63, w = threadIdx.x >> 6;
    const int r0 = blockIdx.x * 32;

    auto stage_load = [&](int s, int buf) {
        #pragma unroll
        for (int i = 0; i < 8; i++) {
            int r = i * 4 + w;                     // wave-uniform row
            const float* g = idx + (size_t)(r0 + r) * 1024 + s * 256 + lane * 4;
            load_lds16(g, &As[buf][r][0]);         // one full 1KB contiguous row-chunk
        }
    };

    const f32x4 z4 = {0.f, 0.f, 0.f, 0.f};
    f32x4 acc[2][3];
    #pragma unroll
    for (int mt = 0; mt < 2; mt++)
        #pragma unroll
        for (int j = 0; j < 3; j++) acc[mt][j] = z4;

    stage_load(0, 0);
    for (int s = 0; s < 4; s++) {
        __syncthreads();                           // stage s LDS ready (vmcnt drained)
        if (s < 3) stage_load(s + 1, (s + 1) & 1); // prefetch overlaps compute(s)
        const int buf = s & 1;
        #pragma unroll
        for (int kk = 0; kk < 8; kk++) {
            bf16x8 aF[2];
            #pragma unroll
            for (int mt = 0; mt < 2; mt++) {
                const float* ap = &As[buf][mt * 16 + (lane & 15)][kk * 32 + (lane >> 4) * 8];
                float4 lo = *(const float4*)ap;
                float4 hi = *(const float4*)(ap + 4);
                bf16x8 a;
                a[0] = (short)f2bf(lo.x); a[1] = (short)f2bf(lo.y);
                a[2] = (short)f2bf(lo.z); a[3] = (short)f2bf(lo.w);
                a[4] = (short)f2bf(hi.x); a[5] = (short)f2bf(hi.y);
                a[6] = (short)f2bf(hi.z); a[7] = (short)f2bf(hi.w);
                aF[mt] = a;
            }
            const unsigned short* Bp = WB + (size_t)(((s * 8 + kk) * 12) * 64 + lane) * 8;
            #pragma unroll
            for (int j = 0; j < 3; j++) {
                int nt = w + j * 4;
                bf16x8 bb = *(const bf16x8*)(Bp + nt * 512);   // 1KB coalesced, L2-hot
                acc[0][j] = MFMA16(aF[0], bb, acc[0][j]);
                acc[1][j] = MFMA16(aF[1], bb, acc[1][j]);
            }
        }
    }

    // epilogue: C/D layout col=lane&15, row=(lane>>4)*4+reg.
    // n = 16w + 64j + (lane&15) -> type j (0=Q 1=K 2=V), h = 16w + (lane&15).
    const int h = w * 16 + (lane & 15);
    #pragma unroll
    for (int j = 0; j < 3; j++) {
        float bias = (j == 0) ? bq[h] : (j == 1) ? bk[h] * 0.03125f : bv[h];
        #pragma unroll
        for (int mt = 0; mt < 2; mt++) {
            int rbase = r0 + mt * 16 + (lane >> 4) * 4;
            #pragma unroll
            for (int reg = 0; reg < 4; reg++) {
                int r = rbase + reg;
                unsigned short v = f2bf(acc[mt][j][reg] + bias);
                if (j == 0) {
                    Q[(size_t)r * 64 + h] = v;
                } else {
                    int b = r >> 12, t = r & 4095;
                    unsigned short* dst = (j == 1) ? Kt : Vt;
                    dst[(size_t)b * 262144 + h * 4096 + t] = v;
                }
            }
        }
    }
}

// ---------------------------------------------------------------------------
// K2: partial M over 32 T-chunks of 128: part[b][c] = Kt_chunk @ Vt_chunk^T (fp32)
__global__ __launch_bounds__(256) void ktv_partial(
    const unsigned short* __restrict__ Kt, const unsigned short* __restrict__ Vt,
    float* __restrict__ part) {
    const int lane = threadIdx.x & 63, wave = threadIdx.x >> 6;
    const int c = blockIdx.x, b = blockIdx.y;
    const unsigned short* Kb = Kt + (size_t)b * 262144;
    const unsigned short* Vb = Vt + (size_t)b * 262144;
    const f32x4 z4 = {0.f, 0.f, 0.f, 0.f};
    f32x4 acc[4] = {z4, z4, z4, z4};
    const int m  = 16 * wave + (lane & 15);
    const int tq = (lane >> 4) * 8;
    #pragma unroll
    for (int it = 0; it < 4; it++) {
        int t0 = c * 128 + it * 32 + tq;
        bf16x8 a = *(const bf16x8*)&Kb[(size_t)m * 4096 + t0];
        #pragma unroll
        for (int nt = 0; nt < 4; nt++) {
            bf16x8 bb = *(const bf16x8*)&Vb[(size_t)(nt * 16 + (lane & 15)) * 4096 + t0];
            acc[nt] = MFMA16(a, bb, acc[nt]);
        }
    }
    float* P = part + (size_t)(b * 32 + c) * 4096;
    const int rowb = 16 * wave + (lane >> 4) * 4;
    #pragma unroll
    for (int nt = 0; nt < 4; nt++)
        #pragma unroll
        for (int reg = 0; reg < 4; reg++)
            P[(rowb + reg) * 64 + nt * 16 + (lane & 15)] = acc[nt][reg];
}

// ---------------------------------------------------------------------------
// K3: M reduce over 32 chunks; store TRANSPOSED bf16: Mt[b][h2][h1]
__global__ void reduce_m(const float* __restrict__ part,
                         unsigned short* __restrict__ Mt) {
    int i = blockIdx.x * 256 + threadIdx.x;         // 16384 -> grid 64
    int b = i >> 12, h1 = (i >> 6) & 63, h2 = i & 63;
    float s = 0.f;
    #pragma unroll
    for (int cc = 0; cc < 32; cc++)
        s += part[(size_t)(b * 32 + cc) * 4096 + h1 * 64 + h2];
    Mt[(size_t)b * 4096 + h2 * 64 + h1] = f2bf(s);
}

// ---------------------------------------------------------------------------
// K4: out[r][h2] = Q[r][:] @ M_b[:, h2], fp32 out.
__global__ __launch_bounds__(256) void qm(
    const unsigned short* __restrict__ Q, const unsigned short* __restrict__ Mt,
    float* __restrict__ out) {
    const int lane = threadIdx.x & 63, wave = threadIdx.x >> 6;
    const int r0 = blockIdx.x * 64;
    const int b  = r0 >> 12;
    const f32x4 z4 = {0.f, 0.f, 0.f, 0.f};
    f32x4 acc[4] = {z4, z4, z4, z4};
    const int rr = r0 + 16 * wave + (lane & 15);
    const int kq = (lane >> 4) * 8;
    #pragma unroll
    for (int ks = 0; ks < 2; ks++) {
        int k0 = ks * 32;
        bf16x8 a = *(const bf16x8*)&Q[(size_t)rr * 64 + k0 + kq];
        #pragma unroll
        for (int nt = 0; nt < 4; nt++) {
            bf16x8 bb = *(const bf16x8*)&Mt[(size_t)b * 4096 + (nt * 16 + (lane & 15)) * 64 + k0 + kq];
            acc[nt] = MFMA16(a, bb, acc[nt]);
        }
    }
    const int rowb = r0 + 16 * wave + (lane >> 4) * 4;
    #pragma unroll
    for (int nt = 0; nt < 4; nt++)
        #pragma unroll
        for (int reg = 0; reg < 4; reg++)
            out[(size_t)(rowb + reg) * 64 + nt * 16 + (lane & 15)] = acc[nt][reg];
}

// ---------------------------------------------------------------------------
// Workspace layout:
//   [0, 384K)    WB   (dead after qkv)
//   [0, 2M)      Pp   (written by ktv_partial AFTER qkv -> safe reuse of WB)
//   [2M, 4M)     Q
//   [4M, 6M)     Kt
//   [6M, 8M)     Vt
//   [8M, 8M+32K) Mt
extern "C" void kernel_launch(void* const* d_in, const int* in_sizes, int n_in,
                              void* d_out, int out_size, void* d_ws, size_t ws_size,
                              hipStream_t stream) {
    const float* idx = (const float*)d_in[0];
    const float* Wq  = (const float*)d_in[1];
    const float* bq  = (const float*)d_in[2];
    const float* Wk  = (const float*)d_in[3];
    const float* bk  = (const float*)d_in[4];
    const float* Wv  = (const float*)d_in[5];
    const float* bv  = (const float*)d_in[6];
    float* out = (float*)d_out;

    char* ws = (char*)d_ws;
    unsigned short* WB = (unsigned short*)(ws);
    float*          Pp = (float*)(ws);
    unsigned short* Q  = (unsigned short*)(ws + (2048u << 10));
    unsigned short* Kt = (unsigned short*)(ws + (4096u << 10));
    unsigned short* Vt = (unsigned short*)(ws + (6144u << 10));
    unsigned short* Mt = (unsigned short*)(ws + (8192u << 10));

    hipLaunchKernelGGL(prep,        dim3(96),     dim3(256), 0, stream, Wq, Wk, Wv, WB);
    hipLaunchKernelGGL(qkv,         dim3(512),    dim3(256), 0, stream,
                       idx, WB, bq, bk, bv, Q, Kt, Vt);
    hipLaunchKernelGGL(ktv_partial, dim3(32, 4),  dim3(256), 0, stream, Kt, Vt, Pp);
    hipLaunchKernelGGL(reduce_m,    dim3(64),     dim3(256), 0, stream, Pp, Mt);
    hipLaunchKernelGGL(qm,          dim3(256),    dim3(256), 0, stream, Q, Mt, out);
}

// Round 6
// 128.225 us; speedup vs baseline: 1.0774x; 1.0114x over previous
//
#include <hip/hip_runtime.h>

// B=4, T=4096, E=1024, H=64.
// out = Q @ M_b,  M_b = (1/32) * K_b^T V_b,  Q/K/V = idx@W + b   (linear attention:
// reference applies no mask/softmax). Scale folded into Wk/bk.
//
// R6 key change: each WAVE reads a contiguous 32KB span of idx sequentially
// (block = contiguous 128KB slab) -> ~2048 long sequential DRAM streams instead
// of ~4096+ fine-grained strided ones. Cast to bf16 in-register, stage to LDS
// in MFMA A-fragment layout; single barrier; compute phase touches only LDS +
// L2-hot WB (no global_load_lds in flight -> no vmcnt entanglement).

typedef __attribute__((ext_vector_type(8))) short bf16x8;   // 8 bf16 = 4 VGPRs
typedef __attribute__((ext_vector_type(4))) float f32x4;    // MFMA C/D

#define MFMA16(a, b, c) __builtin_amdgcn_mfma_f32_16x16x32_bf16((a), (b), (c), 0, 0, 0)

__device__ __forceinline__ unsigned short f2bf(float f) {
    unsigned int u = __float_as_uint(f);
    u += 0x7fffu + ((u >> 16) & 1u);          // round-to-nearest-even
    return (unsigned short)(u >> 16);
}

// ---------------------------------------------------------------------------
// K0: weights -> MFMA-fragment order.
// Chunk index t = (kk*12 + nt)*64 + lane holds 8 bf16:
//   W^T[n][k], n = nt*16 + (lane&15), k = kk*32 + (lane>>4)*8 + j.
// n<64 -> Wq, n<128 -> Wk * 1/32, else Wv.   (W is [k][h] in memory)
__global__ void prep(const float* __restrict__ Wq, const float* __restrict__ Wk,
                     const float* __restrict__ Wv, unsigned short* __restrict__ WB) {
    int t = blockIdx.x * 256 + threadIdx.x;   // 96 blocks -> 24576 chunks
    int kki = t / 768;
    int rem = t - kki * 768;
    int nt = rem >> 6, lane = rem & 63;
    int n = nt * 16 + (lane & 15);
    int kb = kki * 32 + ((lane >> 4) * 8);
    int mm = n >> 6, h = n & 63;
    const float* W = (mm == 0) ? Wq : (mm == 1) ? Wk : Wv;
    float sc = (mm == 1) ? 0.03125f : 1.0f;
    bf16x8 v;
    #pragma unroll
    for (int j = 0; j < 8; j++) v[j] = (short)f2bf(W[(size_t)(kb + j) * 64 + h] * sc);
    *(bf16x8*)(WB + (size_t)t * 8) = v;
}

// ---------------------------------------------------------------------------
// K1: fused QKV projection — sequential per-wave idx streaming.
// Block = 32 rows (contiguous 128KB of idx), 4 waves; grid 512 (2 blocks/CU).
// Stage: wave w reads rows [8w,8w+8) = 32KB front-to-back, 8 float4 loads in
// flight per batch, cast fp32->bf16, ds_write_b64 into A-fragment-friendly LDS
// (row stride 1032 shorts -> 2-way bank access, free). ONE barrier.
// Compute: 32 kk x (2 A-frag ds_read_b128 + 3 B-frag 1KB L2 loads + 6 MFMA);
// each wave owns n-tiles {w, w+4, w+8} (one h-slice each of Q/K/V).
__global__ __launch_bounds__(256, 2) void qkv(
    const float* __restrict__ idx, const unsigned short* __restrict__ WB,
    const float* __restrict__ bq, const float* __restrict__ bk, const float* __restrict__ bv,
    unsigned short* __restrict__ Q, unsigned short* __restrict__ Kt,
    unsigned short* __restrict__ Vt) {
    __shared__ unsigned short As[32 * 1032];       // 66KB; row stride 1032 (+8 pad)
    const int lane = threadIdx.x & 63, w = threadIdx.x >> 6;
    const int r0 = blockIdx.x * 32;

    // ---- stage: contiguous 32KB per wave ----
    const float* src = idx + (size_t)(r0 + w * 8) * 1024;
    #pragma unroll
    for (int batch = 0; batch < 4; batch++) {
        float4 v[8];
        #pragma unroll
        for (int j = 0; j < 8; j++)
            v[j] = *(const float4*)(src + (size_t)(batch * 8 + j) * 256 + lane * 4);
        #pragma unroll
        for (int j = 0; j < 8; j++) {
            int i   = batch * 8 + j;
            int row = w * 8 + (i >> 2);            // 4 chunks of 256 floats per row
            int k   = (i & 3) * 256 + lane * 4;
            unsigned int lo = ((unsigned int)f2bf(v[j].y) << 16) | f2bf(v[j].x);
            unsigned int hi = ((unsigned int)f2bf(v[j].w) << 16) | f2bf(v[j].z);
            uint2 p; p.x = lo; p.y = hi;
            *(uint2*)(As + (size_t)row * 1032 + k) = p;   // ds_write_b64, 2-way banks
        }
    }
    __syncthreads();

    // ---- compute: pure LDS + L2-hot WB ----
    const f32x4 z4 = {0.f, 0.f, 0.f, 0.f};
    f32x4 acc[2][3];
    #pragma unroll
    for (int mt = 0; mt < 2; mt++)
        #pragma unroll
        for (int j = 0; j < 3; j++) acc[mt][j] = z4;

    const int al = lane & 15;                      // row within m-tile
    const int kq = (lane >> 4) * 8;                // k offset within kk-chunk
    #pragma unroll 4
    for (int kk = 0; kk < 32; kk++) {
        bf16x8 a0 = *(const bf16x8*)(As + (size_t)al * 1032 + kk * 32 + kq);
        bf16x8 a1 = *(const bf16x8*)(As + (size_t)(16 + al) * 1032 + kk * 32 + kq);
        const unsigned short* Bp = WB + (size_t)((kk * 12) * 64 + lane) * 8;
        #pragma unroll
        for (int j = 0; j < 3; j++) {
            int nt = w + j * 4;
            bf16x8 bb = *(const bf16x8*)(Bp + nt * 512);   // 1KB coalesced, L2-hot
            acc[0][j] = MFMA16(a0, bb, acc[0][j]);
            acc[1][j] = MFMA16(a1, bb, acc[1][j]);
        }
    }

    // epilogue: C/D layout col=lane&15, row=(lane>>4)*4+reg.
    // n = 16w + 64j + (lane&15) -> type j (0=Q 1=K 2=V), h = 16w + (lane&15).
    const int h = w * 16 + (lane & 15);
    #pragma unroll
    for (int j = 0; j < 3; j++) {
        float bias = (j == 0) ? bq[h] : (j == 1) ? bk[h] * 0.03125f : bv[h];
        #pragma unroll
        for (int mt = 0; mt < 2; mt++) {
            int rbase = r0 + mt * 16 + (lane >> 4) * 4;
            #pragma unroll
            for (int reg = 0; reg < 4; reg++) {
                int r = rbase + reg;
                unsigned short v = f2bf(acc[mt][j][reg] + bias);
                if (j == 0) {
                    Q[(size_t)r * 64 + h] = v;
                } else {
                    int b = r >> 12, t = r & 4095;
                    unsigned short* dst = (j == 1) ? Kt : Vt;
                    dst[(size_t)b * 262144 + h * 4096 + t] = v;
                }
            }
        }
    }
}

// ---------------------------------------------------------------------------
// K2: partial M over 32 T-chunks of 128: part[b][c] = Kt_chunk @ Vt_chunk^T (fp32)
__global__ __launch_bounds__(256) void ktv_partial(
    const unsigned short* __restrict__ Kt, const unsigned short* __restrict__ Vt,
    float* __restrict__ part) {
    const int lane = threadIdx.x & 63, wave = threadIdx.x >> 6;
    const int c = blockIdx.x, b = blockIdx.y;
    const unsigned short* Kb = Kt + (size_t)b * 262144;
    const unsigned short* Vb = Vt + (size_t)b * 262144;
    const f32x4 z4 = {0.f, 0.f, 0.f, 0.f};
    f32x4 acc[4] = {z4, z4, z4, z4};
    const int m  = 16 * wave + (lane & 15);
    const int tq = (lane >> 4) * 8;
    #pragma unroll
    for (int it = 0; it < 4; it++) {
        int t0 = c * 128 + it * 32 + tq;
        bf16x8 a = *(const bf16x8*)&Kb[(size_t)m * 4096 + t0];
        #pragma unroll
        for (int nt = 0; nt < 4; nt++) {
            bf16x8 bb = *(const bf16x8*)&Vb[(size_t)(nt * 16 + (lane & 15)) * 4096 + t0];
            acc[nt] = MFMA16(a, bb, acc[nt]);
        }
    }
    float* P = part + (size_t)(b * 32 + c) * 4096;
    const int rowb = 16 * wave + (lane >> 4) * 4;
    #pragma unroll
    for (int nt = 0; nt < 4; nt++)
        #pragma unroll
        for (int reg = 0; reg < 4; reg++)
            P[(rowb + reg) * 64 + nt * 16 + (lane & 15)] = acc[nt][reg];
}

// ---------------------------------------------------------------------------
// K3: M reduce over 32 chunks; store TRANSPOSED bf16: Mt[b][h2][h1]
__global__ void reduce_m(const float* __restrict__ part,
                         unsigned short* __restrict__ Mt) {
    int i = blockIdx.x * 256 + threadIdx.x;         // 16384 -> grid 64
    int b = i >> 12, h1 = (i >> 6) & 63, h2 = i & 63;
    float s = 0.f;
    #pragma unroll
    for (int cc = 0; cc < 32; cc++)
        s += part[(size_t)(b * 32 + cc) * 4096 + h1 * 64 + h2];
    Mt[(size_t)b * 4096 + h2 * 64 + h1] = f2bf(s);
}

// ---------------------------------------------------------------------------
// K4: out[r][h2] = Q[r][:] @ M_b[:, h2], fp32 out.
__global__ __launch_bounds__(256) void qm(
    const unsigned short* __restrict__ Q, const unsigned short* __restrict__ Mt,
    float* __restrict__ out) {
    const int lane = threadIdx.x & 63, wave = threadIdx.x >> 6;
    const int r0 = blockIdx.x * 64;
    const int b  = r0 >> 12;
    const f32x4 z4 = {0.f, 0.f, 0.f, 0.f};
    f32x4 acc[4] = {z4, z4, z4, z4};
    const int rr = r0 + 16 * wave + (lane & 15);
    const int kq = (lane >> 4) * 8;
    #pragma unroll
    for (int ks = 0; ks < 2; ks++) {
        int k0 = ks * 32;
        bf16x8 a = *(const bf16x8*)&Q[(size_t)rr * 64 + k0 + kq];
        #pragma unroll
        for (int nt = 0; nt < 4; nt++) {
            bf16x8 bb = *(const bf16x8*)&Mt[(size_t)b * 4096 + (nt * 16 + (lane & 15)) * 64 + k0 + kq];
            acc[nt] = MFMA16(a, bb, acc[nt]);
        }
    }
    const int rowb = r0 + 16 * wave + (lane >> 4) * 4;
    #pragma unroll
    for (int nt = 0; nt < 4; nt++)
        #pragma unroll
        for (int reg = 0; reg < 4; reg++)
            out[(size_t)(rowb + reg) * 64 + nt * 16 + (lane & 15)] = acc[nt][reg];
}

// ---------------------------------------------------------------------------
// Workspace layout:
//   [0, 384K)    WB   (dead after qkv)
//   [0, 2M)      Pp   (written by ktv_partial AFTER qkv -> safe reuse of WB)
//   [2M, 4M)     Q
//   [4M, 6M)     Kt
//   [6M, 8M)     Vt
//   [8M, 8M+32K) Mt
extern "C" void kernel_launch(void* const* d_in, const int* in_sizes, int n_in,
                              void* d_out, int out_size, void* d_ws, size_t ws_size,
                              hipStream_t stream) {
    const float* idx = (const float*)d_in[0];
    const float* Wq  = (const float*)d_in[1];
    const float* bq  = (const float*)d_in[2];
    const float* Wk  = (const float*)d_in[3];
    const float* bk  = (const float*)d_in[4];
    const float* Wv  = (const float*)d_in[5];
    const float* bv  = (const float*)d_in[6];
    float* out = (float*)d_out;

    char* ws = (char*)d_ws;
    unsigned short* WB = (unsigned short*)(ws);
    float*          Pp = (float*)(ws);
    unsigned short* Q  = (unsigned short*)(ws + (2048u << 10));
    unsigned short* Kt = (unsigned short*)(ws + (4096u << 10));
    unsigned short* Vt = (unsigned short*)(ws + (6144u << 10));
    unsigned short* Mt = (unsigned short*)(ws + (8192u << 10));

    hipLaunchKernelGGL(prep,        dim3(96),     dim3(256), 0, stream, Wq, Wk, Wv, WB);
    hipLaunchKernelGGL(qkv,         dim3(512),    dim3(256), 0, stream,
                       idx, WB, bq, bk, bv, Q, Kt, Vt);
    hipLaunchKernelGGL(ktv_partial, dim3(32, 4),  dim3(256), 0, stream, Kt, Vt, Pp);
    hipLaunchKernelGGL(reduce_m,    dim3(64),     dim3(256), 0, stream, Pp, Mt);
    hipLaunchKernelGGL(qm,          dim3(256),    dim3(256), 0, stream, Q, Mt, out);
}

// Round 7
// 125.565 us; speedup vs baseline: 1.1002x; 1.0212x over previous
//
#include <hip/hip_runtime.h>

// B=4, T=4096, E=1024, H=64.
// out = Q @ M_b,  M_b = (1/32) * K_b^T V_b,  Q/K/V = idx@W + b   (linear attention:
// reference applies no mask/softmax). Scale folded into Wk/bk.
//
// R7: qkv BM=16, grid 1024 (4 blocks/CU, 16 waves/CU), register double-buffered
// B-fragment prefetch + 1-deep A ds_read prefetch (cover exposed L2/LDS latency),
// and LDS-transposed epilogue (coalesced 8B stores instead of 2B line-scatter).

typedef __attribute__((ext_vector_type(8))) short bf16x8;   // 8 bf16 = 4 VGPRs
typedef __attribute__((ext_vector_type(4))) float f32x4;    // MFMA C/D

#define MFMA16(a, b, c) __builtin_amdgcn_mfma_f32_16x16x32_bf16((a), (b), (c), 0, 0, 0)

__device__ __forceinline__ unsigned short f2bf(float f) {
    unsigned int u = __float_as_uint(f);
    u += 0x7fffu + ((u >> 16) & 1u);          // round-to-nearest-even
    return (unsigned short)(u >> 16);
}

// ---------------------------------------------------------------------------
// K0: weights -> MFMA-fragment order.
// Chunk index t = (kk*12 + nt)*64 + lane holds 8 bf16:
//   W^T[n][k], n = nt*16 + (lane&15), k = kk*32 + (lane>>4)*8 + j.
// n<64 -> Wq, n<128 -> Wk * 1/32, else Wv.   (W is [k][h] in memory)
__global__ void prep(const float* __restrict__ Wq, const float* __restrict__ Wk,
                     const float* __restrict__ Wv, unsigned short* __restrict__ WB) {
    int t = blockIdx.x * 256 + threadIdx.x;   // 96 blocks -> 24576 chunks
    int kki = t / 768;
    int rem = t - kki * 768;
    int nt = rem >> 6, lane = rem & 63;
    int n = nt * 16 + (lane & 15);
    int kb = kki * 32 + ((lane >> 4) * 8);
    int mm = n >> 6, h = n & 63;
    const float* W = (mm == 0) ? Wq : (mm == 1) ? Wk : Wv;
    float sc = (mm == 1) ? 0.03125f : 1.0f;
    bf16x8 v;
    #pragma unroll
    for (int j = 0; j < 8; j++) v[j] = (short)f2bf(W[(size_t)(kb + j) * 64 + h] * sc);
    *(bf16x8*)(WB + (size_t)t * 8) = v;
}

// ---------------------------------------------------------------------------
// K1: fused QKV projection.
// Block = 16 rows (contiguous 64KB of idx), 4 waves; grid 1024 (4 blocks/CU).
// Stage: wave w reads rows [4w,4w+4) sequentially, 8 float4 in flight/batch,
// cast to bf16, ds_write (row stride 1032 shorts -> benign 2-way banks).
// Compute: 32 kk; per kk: 1 A ds_read_b128 (prefetched 1 ahead) + 3 B 1KB
// L2 loads (register double-buffered, issued a full kk ahead) + 3 MFMAs.
// Epilogue: accs -> LDS (reusing As) -> coalesced 8B/lane stores of Q/Kt/Vt.
__global__ __launch_bounds__(256, 4) void qkv(
    const float* __restrict__ idx, const unsigned short* __restrict__ WB,
    const float* __restrict__ bq, const float* __restrict__ bk, const float* __restrict__ bv,
    unsigned short* __restrict__ Q, unsigned short* __restrict__ Kt,
    unsigned short* __restrict__ Vt) {
    __shared__ unsigned short As[16 * 1032];       // 33 KB
    const int lane = threadIdx.x & 63, w = threadIdx.x >> 6;
    const int r0 = blockIdx.x * 16;

    // ---- stage: contiguous 16KB per wave (4 rows) ----
    const float* src = idx + (size_t)(r0 + w * 4) * 1024;
    #pragma unroll
    for (int batch = 0; batch < 2; batch++) {
        float4 v[8];
        #pragma unroll
        for (int j = 0; j < 8; j++)
            v[j] = *(const float4*)(src + (size_t)(batch * 8 + j) * 256 + lane * 4);
        #pragma unroll
        for (int j = 0; j < 8; j++) {
            int i   = batch * 8 + j;
            int row = w * 4 + (i >> 2);            // 4 chunks of 256 floats per row
            int k   = (i & 3) * 256 + lane * 4;
            unsigned int lo = ((unsigned int)f2bf(v[j].y) << 16) | f2bf(v[j].x);
            unsigned int hi = ((unsigned int)f2bf(v[j].w) << 16) | f2bf(v[j].z);
            uint2 p; p.x = lo; p.y = hi;
            *(uint2*)(As + (size_t)row * 1032 + k) = p;
        }
    }
    __syncthreads();

    // ---- compute: software-pipelined (B 1 kk ahead in regs, A 1 kk ahead) ----
    const f32x4 z4 = {0.f, 0.f, 0.f, 0.f};
    f32x4 acc[3] = {z4, z4, z4};

    const unsigned short* a_base = As + (size_t)(lane & 15) * 1032 + ((lane >> 4) * 8);
    bf16x8 a_c = *(const bf16x8*)(a_base);
    bf16x8 bc[3], bn[3];
    {
        const unsigned short* Bp = WB + (size_t)(lane * 8);
        #pragma unroll
        for (int j = 0; j < 3; j++) bc[j] = *(const bf16x8*)(Bp + (w + j * 4) * 512);
    }
    for (int kk = 0; kk < 32; kk++) {
        bf16x8 a_n = a_c;
        if (kk < 31) {
            const unsigned short* Bp = WB + (size_t)(((kk + 1) * 12) * 64 + lane) * 8;
            #pragma unroll
            for (int j = 0; j < 3; j++) bn[j] = *(const bf16x8*)(Bp + (w + j * 4) * 512);
            a_n = *(const bf16x8*)(a_base + (kk + 1) * 32);
        }
        #pragma unroll
        for (int j = 0; j < 3; j++) acc[j] = MFMA16(a_c, bc[j], acc[j]);
        #pragma unroll
        for (int j = 0; j < 3; j++) bc[j] = bn[j];
        a_c = a_n;
    }

    // ---- epilogue via LDS transpose (As is dead) ----
    __syncthreads();                               // all A reads done
    unsigned short* Lq = As;                       // [16][64] row-major (1024)
    unsigned short* Lk = As + 1024;                // [64][16] h-major  (1024)
    unsigned short* Lv = As + 2048;                // [64][16] h-major  (1024)
    const int h   = w * 16 + (lane & 15);
    const int row = (lane >> 4) * 4;               // + reg
    {
        float bias0 = bq[h], bias1 = bk[h] * 0.03125f, bias2 = bv[h];
        #pragma unroll
        for (int reg = 0; reg < 4; reg++) {
            int r = row + reg;
            Lq[r * 64 + h] = f2bf(acc[0][reg] + bias0);
            Lk[h * 16 + r] = f2bf(acc[1][reg] + bias1);
            Lv[h * 16 + r] = f2bf(acc[2][reg] + bias2);
        }
    }
    __syncthreads();
    {
        const int tt = threadIdx.x;
        // Q: [16 rows][64 h], fully coalesced 8B/lane
        int qr = tt >> 4, qh = (tt & 15) * 4;
        *(uint2*)(Q + (size_t)(r0 + qr) * 64 + qh) = *(const uint2*)(Lq + qr * 64 + qh);
        // Kt/Vt: [h][t], 8B/lane, 4 lanes per h
        int b = r0 >> 12, t0 = r0 & 4095;
        int hh = tt >> 2, tc = (tt & 3) * 4;
        *(uint2*)(Kt + (size_t)b * 262144 + hh * 4096 + t0 + tc) =
            *(const uint2*)(Lk + hh * 16 + tc);
        *(uint2*)(Vt + (size_t)b * 262144 + hh * 4096 + t0 + tc) =
            *(const uint2*)(Lv + hh * 16 + tc);
    }
}

// ---------------------------------------------------------------------------
// K2: partial M over 32 T-chunks of 128: part[b][c] = Kt_chunk @ Vt_chunk^T (fp32)
__global__ __launch_bounds__(256) void ktv_partial(
    const unsigned short* __restrict__ Kt, const unsigned short* __restrict__ Vt,
    float* __restrict__ part) {
    const int lane = threadIdx.x & 63, wave = threadIdx.x >> 6;
    const int c = blockIdx.x, b = blockIdx.y;
    const unsigned short* Kb = Kt + (size_t)b * 262144;
    const unsigned short* Vb = Vt + (size_t)b * 262144;
    const f32x4 z4 = {0.f, 0.f, 0.f, 0.f};
    f32x4 acc[4] = {z4, z4, z4, z4};
    const int m  = 16 * wave + (lane & 15);
    const int tq = (lane >> 4) * 8;
    #pragma unroll
    for (int it = 0; it < 4; it++) {
        int t0 = c * 128 + it * 32 + tq;
        bf16x8 a = *(const bf16x8*)&Kb[(size_t)m * 4096 + t0];
        #pragma unroll
        for (int nt = 0; nt < 4; nt++) {
            bf16x8 bb = *(const bf16x8*)&Vb[(size_t)(nt * 16 + (lane & 15)) * 4096 + t0];
            acc[nt] = MFMA16(a, bb, acc[nt]);
        }
    }
    float* P = part + (size_t)(b * 32 + c) * 4096;
    const int rowb = 16 * wave + (lane >> 4) * 4;
    #pragma unroll
    for (int nt = 0; nt < 4; nt++)
        #pragma unroll
        for (int reg = 0; reg < 4; reg++)
            P[(rowb + reg) * 64 + nt * 16 + (lane & 15)] = acc[nt][reg];
}

// ---------------------------------------------------------------------------
// K3: M reduce over 32 chunks; store TRANSPOSED bf16: Mt[b][h2][h1]
__global__ void reduce_m(const float* __restrict__ part,
                         unsigned short* __restrict__ Mt) {
    int i = blockIdx.x * 256 + threadIdx.x;         // 16384 -> grid 64
    int b = i >> 12, h1 = (i >> 6) & 63, h2 = i & 63;
    float s = 0.f;
    #pragma unroll
    for (int cc = 0; cc < 32; cc++)
        s += part[(size_t)(b * 32 + cc) * 4096 + h1 * 64 + h2];
    Mt[(size_t)b * 4096 + h2 * 64 + h1] = f2bf(s);
}

// ---------------------------------------------------------------------------
// K4: out[r][h2] = Q[r][:] @ M_b[:, h2], fp32 out.
__global__ __launch_bounds__(256) void qm(
    const unsigned short* __restrict__ Q, const unsigned short* __restrict__ Mt,
    float* __restrict__ out) {
    const int lane = threadIdx.x & 63, wave = threadIdx.x >> 6;
    const int r0 = blockIdx.x * 64;
    const int b  = r0 >> 12;
    const f32x4 z4 = {0.f, 0.f, 0.f, 0.f};
    f32x4 acc[4] = {z4, z4, z4, z4};
    const int rr = r0 + 16 * wave + (lane & 15);
    const int kq = (lane >> 4) * 8;
    #pragma unroll
    for (int ks = 0; ks < 2; ks++) {
        int k0 = ks * 32;
        bf16x8 a = *(const bf16x8*)&Q[(size_t)rr * 64 + k0 + kq];
        #pragma unroll
        for (int nt = 0; nt < 4; nt++) {
            bf16x8 bb = *(const bf16x8*)&Mt[(size_t)b * 4096 + (nt * 16 + (lane & 15)) * 64 + k0 + kq];
            acc[nt] = MFMA16(a, bb, acc[nt]);
        }
    }
    const int rowb = r0 + 16 * wave + (lane >> 4) * 4;
    #pragma unroll
    for (int nt = 0; nt < 4; nt++)
        #pragma unroll
        for (int reg = 0; reg < 4; reg++)
            out[(size_t)(rowb + reg) * 64 + nt * 16 + (lane & 15)] = acc[nt][reg];
}

// ---------------------------------------------------------------------------
// Workspace layout:
//   [0, 384K)    WB   (dead after qkv)
//   [0, 2M)      Pp   (written by ktv_partial AFTER qkv -> safe reuse of WB)
//   [2M, 4M)     Q
//   [4M, 6M)     Kt
//   [6M, 8M)     Vt
//   [8M, 8M+32K) Mt
extern "C" void kernel_launch(void* const* d_in, const int* in_sizes, int n_in,
                              void* d_out, int out_size, void* d_ws, size_t ws_size,
                              hipStream_t stream) {
    const float* idx = (const float*)d_in[0];
    const float* Wq  = (const float*)d_in[1];
    const float* bq  = (const float*)d_in[2];
    const float* Wk  = (const float*)d_in[3];
    const float* bk  = (const float*)d_in[4];
    const float* Wv  = (const float*)d_in[5];
    const float* bv  = (const float*)d_in[6];
    float* out = (float*)d_out;

    char* ws = (char*)d_ws;
    unsigned short* WB = (unsigned short*)(ws);
    float*          Pp = (float*)(ws);
    unsigned short* Q  = (unsigned short*)(ws + (2048u << 10));
    unsigned short* Kt = (unsigned short*)(ws + (4096u << 10));
    unsigned short* Vt = (unsigned short*)(ws + (6144u << 10));
    unsigned short* Mt = (unsigned short*)(ws + (8192u << 10));

    hipLaunchKernelGGL(prep,        dim3(96),     dim3(256), 0, stream, Wq, Wk, Wv, WB);
    hipLaunchKernelGGL(qkv,         dim3(1024),   dim3(256), 0, stream,
                       idx, WB, bq, bk, bv, Q, Kt, Vt);
    hipLaunchKernelGGL(ktv_partial, dim3(32, 4),  dim3(256), 0, stream, Kt, Vt, Pp);
    hipLaunchKernelGGL(reduce_m,    dim3(64),     dim3(256), 0, stream, Pp, Mt);
    hipLaunchKernelGGL(qm,          dim3(256),    dim3(256), 0, stream, Q, Mt, out);
}